// Round 1
// 836.446 us; speedup vs baseline: 1.2070x; 1.2070x over previous
//
#include <hip/hip_runtime.h>
#include <math.h>

#define TOKENS 16384
#define HID 768
#define FFN_DIM 3072
#define NEXP 8
#define MAXT 136        // max 256-row padded tiles: floor((32768+8*255)/256)=135, +1 margin

#define RT_TPB 128      // router tokens per block
#define RT_BLOCKS (TOKENS / RT_TPB)

typedef __bf16 bf16x8 __attribute__((ext_vector_type(8)));
typedef float f32x4 __attribute__((ext_vector_type(4)));

#define GLOBAL_AS(p) ((const __attribute__((address_space(1))) void*)(p))
#define LDS_AS(p)    ((__attribute__((address_space(3))) void*)(p))
#define SB0 __builtin_amdgcn_sched_barrier(0)

__device__ __forceinline__ float gelu_f(float x) {
    const float x3 = x * x * x;
    const float z = 0.7978845608028654f * (x + 0.044715f * x3);
    const float e = __expf(2.f * z);
    const float t = 1.f - 2.f / (e + 1.f);   // tanh(z)
    return 0.5f * x * (1.f + t);
}

__device__ __forceinline__ unsigned short f2bf(float v) {
    return __builtin_bit_cast(unsigned short, (__bf16)v);
}

// ---------------- router (block-aggregated atomics) ----------------
__global__ void __launch_bounds__(512) router_kernel(
    const float* __restrict__ x, const float* __restrict__ rw,
    const float* __restrict__ rb,
    float* __restrict__ out_rw, float* __restrict__ out_dm,
    float* __restrict__ out_logits,
    int* __restrict__ counts, float* __restrict__ probsum,
    float* __restrict__ gatesum, int* __restrict__ lists,
    float* __restrict__ glists)
{
    __shared__ int s_cnt[NEXP], s_base[NEXP];
    __shared__ float s_prob[NEXP], s_gate[NEXP];
    __shared__ int s_e1[RT_TPB], s_s1[RT_TPB], s_e2[RT_TPB], s_s2[RT_TPB];
    __shared__ float s_g1v[RT_TPB], s_g2v[RT_TPB];

    const int tid = threadIdx.x;
    if (tid < NEXP) { s_cnt[tid] = 0; s_prob[tid] = 0.f; s_gate[tid] = 0.f; }
    __syncthreads();

    const int wave = tid >> 6, lane = tid & 63;

    for (int it = 0; it < RT_TPB / 8; ++it) {   // 16 tokens per wave
        const int lt = wave * (RT_TPB / 8) + it;
        const int t = blockIdx.x * RT_TPB + lt;
        const float* xr = x + (size_t)t * HID;
        float acc[NEXP];
#pragma unroll
        for (int e = 0; e < NEXP; ++e) acc[e] = 0.f;
#pragma unroll
        for (int j = 0; j < 12; ++j) {
            const int i = lane + (j << 6);
            const float xv = xr[i];
            const float4 a = ((const float4*)(rw + (size_t)i * NEXP))[0];
            const float4 b = ((const float4*)(rw + (size_t)i * NEXP))[1];
            acc[0] += xv * a.x; acc[1] += xv * a.y; acc[2] += xv * a.z; acc[3] += xv * a.w;
            acc[4] += xv * b.x; acc[5] += xv * b.y; acc[6] += xv * b.z; acc[7] += xv * b.w;
        }
#pragma unroll
        for (int off = 32; off > 0; off >>= 1)
#pragma unroll
            for (int e = 0; e < NEXP; ++e) acc[e] += __shfl_down(acc[e], off, 64);

        if (lane == 0) {
            float lg[NEXP];
            float m = -1e30f;
#pragma unroll
            for (int e = 0; e < NEXP; ++e) { lg[e] = acc[e] + rb[e]; m = fmaxf(m, lg[e]); }
            float ex[NEXP]; float s = 0.f;
#pragma unroll
            for (int e = 0; e < NEXP; ++e) { ex[e] = expf(lg[e] - m); s += ex[e]; }
            const float inv = 1.f / s;
            float* lrow = out_logits + (size_t)t * NEXP;
            float* prow = out_rw + (size_t)t * NEXP;
#pragma unroll
            for (int e = 0; e < NEXP; ++e) {
                lrow[e] = lg[e];
                const float p = ex[e] * inv;
                prow[e] = p;
                atomicAdd(&s_prob[e], p);
            }
            int i1 = 0;
#pragma unroll
            for (int e = 1; e < NEXP; ++e) if (lg[e] > lg[i1]) i1 = e;
            int i2 = (i1 == 0) ? 1 : 0;
#pragma unroll
            for (int e = 0; e < NEXP; ++e) if (e != i1 && lg[e] > lg[i2]) i2 = e;
            const float e2 = expf(lg[i2] - lg[i1]);
            const float g1 = 1.f / (1.f + e2);
            const float g2 = e2 / (1.f + e2);
            out_dm[(size_t)t * NEXP + i1] = g1;
            out_dm[(size_t)t * NEXP + i2] = g2;
            atomicAdd(&s_gate[i1], g1);
            atomicAdd(&s_gate[i2], g2);
            s_e1[lt] = i1; s_s1[lt] = atomicAdd(&s_cnt[i1], 1); s_g1v[lt] = g1;
            s_e2[lt] = i2; s_s2[lt] = atomicAdd(&s_cnt[i2], 1); s_g2v[lt] = g2;
        }
    }
    __syncthreads();
    if (tid < NEXP) {
        s_base[tid] = atomicAdd(&counts[tid], s_cnt[tid]);
        atomicAdd(&probsum[tid], s_prob[tid]);
        atomicAdd(&gatesum[tid], s_gate[tid]);
    }
    __syncthreads();
    if (tid < RT_TPB) {
        const int t = blockIdx.x * RT_TPB + tid;
        int e = s_e1[tid]; int p = s_base[e] + s_s1[tid];
        lists[e * TOKENS + p] = t; glists[e * TOKENS + p] = s_g1v[tid];
        e = s_e2[tid]; p = s_base[e] + s_s2[tid];
        lists[e * TOKENS + p] = t; glists[e * TOKENS + p] = s_g2v[tid];
    }
}

// ---------------- finalize: aux loss + padded (256) segment offsets ----------------
__global__ void finalize_kernel(const int* __restrict__ counts,
                                const float* __restrict__ probsum,
                                const float* __restrict__ gatesum,
                                int* __restrict__ poffs,
                                float* __restrict__ out_aux)
{
    if (threadIdx.x == 0 && blockIdx.x == 0) {
        float s = 0.f; int po = 0;
        for (int e = 0; e < NEXP; ++e) {
            poffs[e] = po;
            po += ((counts[e] + 255) >> 8) << 8;   // pad each segment to 256
            s += (probsum[e] / (float)TOKENS) * (gatesum[e] / (float)TOKENS);
        }
        poffs[NEXP] = po;
        *out_aux = s * (float)NEXP;
    }
}

// ---------------- gather X into segment order, fp32 -> bf16 ----------------
// one block per padded row; pad rows zeroed
__global__ void __launch_bounds__(192) gatherx_kernel(
    const float* __restrict__ x, const int* __restrict__ counts,
    const int* __restrict__ poffs, const int* __restrict__ lists,
    unsigned short* __restrict__ Xg)
{
    const int r = blockIdx.x;
    if (r >= poffs[NEXP]) return;
    int e = 0;
#pragma unroll
    for (int q = 1; q < NEXP; ++q) e += (r >= poffs[q]);
    const int ri = r - poffs[e];
    const int tid = threadIdx.x;
    uint2 o = make_uint2(0u, 0u);
    if (ri < counts[e]) {
        const int tok = lists[e * TOKENS + ri];
        const float4 v = *(const float4*)&x[(size_t)tok * HID + tid * 4];
        o.x = (unsigned)f2bf(v.x) | ((unsigned)f2bf(v.y) << 16);
        o.y = (unsigned)f2bf(v.z) | ((unsigned)f2bf(v.w) << 16);
    }
    *(uint2*)&Xg[(size_t)r * HID + tid * 4] = o;
}

// fp32 [E][R][C] -> bf16 transposed [E][C][R]
__global__ void __launch_bounds__(256) convT_kernel(const float* __restrict__ in,
                                                    unsigned short* __restrict__ out,
                                                    int R, int C)
{
    __shared__ float sT[32][65];
    const int e = blockIdx.z;
    const float* in_e = in + (size_t)e * R * C;
    unsigned short* out_e = out + (size_t)e * R * C;
    const int r0 = blockIdx.y * 64;
    const int c0 = blockIdx.x * 32;
    const int tid = threadIdx.x;
    const int rr = tid >> 3, c4 = (tid & 7) * 4;
#pragma unroll
    for (int half = 0; half < 2; ++half) {
        const int r = rr + half * 32;
        const float4 v = *(const float4*)&in_e[(size_t)(r0 + r) * C + c0 + c4];
        sT[c4 + 0][r] = v.x; sT[c4 + 1][r] = v.y;
        sT[c4 + 2][r] = v.z; sT[c4 + 3][r] = v.w;
    }
    __syncthreads();
    const int c = tid >> 3, u = tid & 7;
    uint4 pk;
    const float* sr = &sT[c][u * 8];
    pk.x = (unsigned)f2bf(sr[0]) | ((unsigned)f2bf(sr[1]) << 16);
    pk.y = (unsigned)f2bf(sr[2]) | ((unsigned)f2bf(sr[3]) << 16);
    pk.z = (unsigned)f2bf(sr[4]) | ((unsigned)f2bf(sr[5]) << 16);
    pk.w = (unsigned)f2bf(sr[6]) | ((unsigned)f2bf(sr[7]) << 16);
    *(uint4*)&out_e[(size_t)(c0 + c) * R + r0 + u * 8] = pk;
}

// =====================================================================
// 256x128-tile, 8-wave, BK=64, depth-3 rotating LDS, counted vmcnt(6),
// XOR-swizzled LDS (group ^= row&7, applied via pre-swizzled gload src
// and swizzled ds_read address), setprio around MFMA cluster.
// LDS slot layout (bf16 elements): A tile [256][64] at +0, B tile
// [128][64] at +16384. Slot stride 24576 elements (48KB). 3 slots.
// =====================================================================

// stage one K-step (6 global_load_lds per wave: A rows wv*32..+31, B rows wv*16..+15)
#define STAGE_AB(os_, kt_) do {                                                                          \
    const unsigned short* _a = aSrc + (kt_) * 64;                                                        \
    const unsigned short* _b = bSrc + (kt_) * 64;                                                        \
    __builtin_amdgcn_global_load_lds(GLOBAL_AS(_a + (size_t)(wv*32 +  0) * KS), LDS_AS(&lds[(os_) +         (wv*32 +  0) * 64]), 16, 0, 0); \
    __builtin_amdgcn_global_load_lds(GLOBAL_AS(_a + (size_t)(wv*32 +  8) * KS), LDS_AS(&lds[(os_) +         (wv*32 +  8) * 64]), 16, 0, 0); \
    __builtin_amdgcn_global_load_lds(GLOBAL_AS(_a + (size_t)(wv*32 + 16) * KS), LDS_AS(&lds[(os_) +         (wv*32 + 16) * 64]), 16, 0, 0); \
    __builtin_amdgcn_global_load_lds(GLOBAL_AS(_a + (size_t)(wv*32 + 24) * KS), LDS_AS(&lds[(os_) +         (wv*32 + 24) * 64]), 16, 0, 0); \
    __builtin_amdgcn_global_load_lds(GLOBAL_AS(_b + (size_t)(wv*16 +  0) * KS), LDS_AS(&lds[(os_) + 16384 + (wv*16 +  0) * 64]), 16, 0, 0); \
    __builtin_amdgcn_global_load_lds(GLOBAL_AS(_b + (size_t)(wv*16 +  8) * KS), LDS_AS(&lds[(os_) + 16384 + (wv*16 +  8) * 64]), 16, 0, 0); \
} while (0)

// decode: bijective XCD swizzle (m204) then supertile (8 m-tiles x NT n-tiles)
#define DECODE_TILE(NT_) \
    const int nwg = gridDim.x;                                                       \
    const int orig = blockIdx.x;                                                     \
    const int qq = nwg >> 3, rr2 = nwg & 7;                                          \
    const int xcd = orig & 7, pos = orig >> 3;                                       \
    const int wid = (xcd < rr2 ? xcd * (qq + 1) : rr2 * (qq + 1) + (xcd - rr2) * qq) + pos; \
    const int nSuper = tilesPG >> 3;                                                 \
    const int fullB = nSuper * 8 * (NT_);                                            \
    int mt, nti;                                                                     \
    if (wid < fullB) {                                                               \
        const int st = wid / (8 * (NT_));                                            \
        const int lo = wid - st * (8 * (NT_));                                       \
        mt = (st << 3) + (lo & 7);                                                   \
        nti = lo >> 3;                                                               \
    } else {                                                                         \
        const int rem = tilesPG - (nSuper << 3);                                     \
        const int lo = wid - fullB;                                                  \
        mt = (nSuper << 3) + lo % rem;                                               \
        nti = lo / rem;                                                              \
    }

// ---------------- GEMM1: H = gelu(Xg @ W1 + b1), bf16 out ----------------
__global__ void __launch_bounds__(512, 2) gemm1_kernel(
    const unsigned short* __restrict__ Xg, const unsigned short* __restrict__ W1T,
    const float* __restrict__ b1, const int* __restrict__ poffs,
    unsigned short* __restrict__ H, int grBase, int tilesPG)
{
    extern __shared__ __bf16 lds[];
    const int KS = HID;            // 768
    const int NK = HID / 64;       // 12

    DECODE_TILE(FFN_DIM / 128)     // 24 n-tiles
    const int gr = grBase + mt * 256;
    if (gr >= poffs[NEXP]) return;
    int e = 0;
#pragma unroll
    for (int q = 1; q < NEXP; ++q) e += (gr >= poffs[q]);
    const int hbase = gr - grBase;
    const int n0 = nti * 128;

    const int tid = threadIdx.x;
    const int wv = tid >> 6, lane = tid & 63;
    const int wr = wv >> 2, wc = wv & 3;
    const int fr = lane & 15, q4 = lane >> 4, sw = fr & 7;
    const int rlo = lane >> 3;
    const int cswz = ((lane & 7) ^ rlo) << 3;   // pre-swizzled source column (elements)

    const unsigned short* aSrc = Xg + (size_t)(gr + rlo) * KS + cswz;
    const unsigned short* bSrc = W1T + (size_t)e * (HID * FFN_DIM) + (size_t)(n0 + rlo) * KS + cswz;

    const int aRow = (wr * 128 + fr) * 64;      // element offset of A frag base row
    const int bRow = (wc * 32 + fr) * 64;       // element offset of B frag base row
    const int c0 = (q4 ^ sw) << 3;              // swizzled k-group, kk=0
    const int c1 = ((4 + q4) ^ sw) << 3;        // swizzled k-group, kk=32

    f32x4 acc[8][2];
#pragma unroll
    for (int i = 0; i < 8; ++i) { acc[i][0] = (f32x4)(0.f); acc[i][1] = (f32x4)(0.f); }

    int oc = 0, on = 24576, os = 49152;
    STAGE_AB(oc, 0);
    STAGE_AB(on, 1);
    asm volatile("s_waitcnt vmcnt(6)" ::: "memory");
    SB0; __builtin_amdgcn_s_barrier(); SB0;

    for (int kt = 0; kt < NK; ++kt) {
        if (kt + 2 < NK) STAGE_AB(os, kt + 2);
        __builtin_amdgcn_s_setprio(1);
        const bf16x8 b00 = *(const bf16x8*)&lds[oc + 16384 + bRow + c0];
        const bf16x8 b01 = *(const bf16x8*)&lds[oc + 16384 + bRow + c1];
        const bf16x8 b10 = *(const bf16x8*)&lds[oc + 16384 + bRow + 1024 + c0];
        const bf16x8 b11 = *(const bf16x8*)&lds[oc + 16384 + bRow + 1024 + c1];
#pragma unroll
        for (int mi = 0; mi < 8; ++mi) {
            const bf16x8 a0 = *(const bf16x8*)&lds[oc + aRow + mi * 1024 + c0];
            const bf16x8 a1 = *(const bf16x8*)&lds[oc + aRow + mi * 1024 + c1];
            acc[mi][0] = __builtin_amdgcn_mfma_f32_16x16x32_bf16(a0, b00, acc[mi][0], 0, 0, 0);
            acc[mi][0] = __builtin_amdgcn_mfma_f32_16x16x32_bf16(a1, b01, acc[mi][0], 0, 0, 0);
            acc[mi][1] = __builtin_amdgcn_mfma_f32_16x16x32_bf16(a0, b10, acc[mi][1], 0, 0, 0);
            acc[mi][1] = __builtin_amdgcn_mfma_f32_16x16x32_bf16(a1, b11, acc[mi][1], 0, 0, 0);
        }
        __builtin_amdgcn_s_setprio(0);
        if (kt + 1 < NK) {
            SB0;
            if (kt + 2 < NK) asm volatile("s_waitcnt vmcnt(6)" ::: "memory");
            else             asm volatile("s_waitcnt vmcnt(0)" ::: "memory");
            __builtin_amdgcn_s_barrier(); SB0;
        }
        const int t_ = oc; oc = on; on = os; os = t_;
    }

    const float* b1e = b1 + (size_t)e * FFN_DIM;
    const float bias0 = b1e[n0 + wc * 32 + fr];
    const float bias1 = b1e[n0 + wc * 32 + 16 + fr];
    unsigned short* Hcol = H + (size_t)hbase * FFN_DIM + n0 + wc * 32 + fr;
#pragma unroll
    for (int mi = 0; mi < 8; ++mi) {
#pragma unroll
        for (int r = 0; r < 4; ++r) {
            const int m = wr * 128 + mi * 16 + q4 * 4 + r;
            unsigned short* hp = Hcol + (size_t)m * FFN_DIM;
            hp[0]  = f2bf(gelu_f(acc[mi][0][r] + bias0));
            hp[16] = f2bf(gelu_f(acc[mi][1][r] + bias1));
        }
    }
}

// ---------------- GEMM2: out[tok] += gate*(H @ W2 + b2) ----------------
__global__ void __launch_bounds__(512, 2) gemm2_kernel(
    const unsigned short* __restrict__ H, const unsigned short* __restrict__ W2T,
    const float* __restrict__ b2, const int* __restrict__ counts,
    const int* __restrict__ poffs, const int* __restrict__ lists,
    const float* __restrict__ glists, float* __restrict__ out,
    int grBase, int tilesPG)
{
    extern __shared__ __bf16 lds[];
    const int KS = FFN_DIM;          // 3072
    const int NK = FFN_DIM / 64;     // 48

    DECODE_TILE(HID / 128)           // 6 n-tiles
    const int gr = grBase + mt * 256;
    if (gr >= poffs[NEXP]) return;
    int e = 0;
#pragma unroll
    for (int q = 1; q < NEXP; ++q) e += (gr >= poffs[q]);
    const int cnt = counts[e];
    const int m0 = gr - poffs[e];
    const int hbase = gr - grBase;
    const int n0 = nti * 128;

    const int tid = threadIdx.x;
    const int wv = tid >> 6, lane = tid & 63;
    const int wr = wv >> 2, wc = wv & 3;
    const int fr = lane & 15, q4 = lane >> 4, sw = fr & 7;
    const int rlo = lane >> 3;
    const int cswz = ((lane & 7) ^ rlo) << 3;

    const unsigned short* aSrc = H + (size_t)(hbase + rlo) * KS + cswz;
    const unsigned short* bSrc = W2T + (size_t)e * (HID * FFN_DIM) + (size_t)(n0 + rlo) * KS + cswz;

    const int aRow = (wr * 128 + fr) * 64;
    const int bRow = (wc * 32 + fr) * 64;
    const int c0 = (q4 ^ sw) << 3;
    const int c1 = ((4 + q4) ^ sw) << 3;

    f32x4 acc[8][2];
#pragma unroll
    for (int i = 0; i < 8; ++i) { acc[i][0] = (f32x4)(0.f); acc[i][1] = (f32x4)(0.f); }

    int oc = 0, on = 24576, os = 49152;
    STAGE_AB(oc, 0);
    STAGE_AB(on, 1);
    asm volatile("s_waitcnt vmcnt(6)" ::: "memory");
    SB0; __builtin_amdgcn_s_barrier(); SB0;

    for (int kt = 0; kt < NK; ++kt) {
        if (kt + 2 < NK) STAGE_AB(os, kt + 2);
        __builtin_amdgcn_s_setprio(1);
        const bf16x8 b00 = *(const bf16x8*)&lds[oc + 16384 + bRow + c0];
        const bf16x8 b01 = *(const bf16x8*)&lds[oc + 16384 + bRow + c1];
        const bf16x8 b10 = *(const bf16x8*)&lds[oc + 16384 + bRow + 1024 + c0];
        const bf16x8 b11 = *(const bf16x8*)&lds[oc + 16384 + bRow + 1024 + c1];
#pragma unroll
        for (int mi = 0; mi < 8; ++mi) {
            const bf16x8 a0 = *(const bf16x8*)&lds[oc + aRow + mi * 1024 + c0];
            const bf16x8 a1 = *(const bf16x8*)&lds[oc + aRow + mi * 1024 + c1];
            acc[mi][0] = __builtin_amdgcn_mfma_f32_16x16x32_bf16(a0, b00, acc[mi][0], 0, 0, 0);
            acc[mi][0] = __builtin_amdgcn_mfma_f32_16x16x32_bf16(a1, b01, acc[mi][0], 0, 0, 0);
            acc[mi][1] = __builtin_amdgcn_mfma_f32_16x16x32_bf16(a0, b10, acc[mi][1], 0, 0, 0);
            acc[mi][1] = __builtin_amdgcn_mfma_f32_16x16x32_bf16(a1, b11, acc[mi][1], 0, 0, 0);
        }
        __builtin_amdgcn_s_setprio(0);
        if (kt + 1 < NK) {
            SB0;
            if (kt + 2 < NK) asm volatile("s_waitcnt vmcnt(6)" ::: "memory");
            else             asm volatile("s_waitcnt vmcnt(0)" ::: "memory");
            __builtin_amdgcn_s_barrier(); SB0;
        }
        const int t_ = oc; oc = on; on = os; os = t_;
    }

    int* sTok = (int*)(lds + 73728);            // byte 147456
    float* sGate = (float*)(lds + 73728 + 512); // byte 148480
    if (tid < 256) {
        int ri = m0 + tid; if (ri > cnt - 1) ri = cnt - 1;
        sTok[tid] = lists[e * TOKENS + ri];
        sGate[tid] = glists[e * TOKENS + ri];
    }
    __syncthreads();

    const float* b2e = b2 + (size_t)e * HID;
    const float bias0 = b2e[n0 + wc * 32 + fr];
    const float bias1 = b2e[n0 + wc * 32 + 16 + fr];
#pragma unroll
    for (int mi = 0; mi < 8; ++mi) {
#pragma unroll
        for (int r = 0; r < 4; ++r) {
            const int m = wr * 128 + mi * 16 + q4 * 4 + r;
            if (m0 + m < cnt) {
                const int tok = sTok[m];
                const float g = sGate[m];
                float* orow = out + (size_t)tok * HID + n0 + wc * 32 + fr;
                atomicAdd(orow,      g * (acc[mi][0][r] + bias0));
                atomicAdd(orow + 16, g * (acc[mi][1][r] + bias1));
            }
        }
    }
}

// ---------------- fallback fp32 FFN (ws too small) ----------------
#define BM 16
#define KC 64
#define XS 772
#define HS 68
__global__ void __launch_bounds__(256) ffn_kernel(
    const float* __restrict__ x, const float* __restrict__ w1,
    const float* __restrict__ b1, const float* __restrict__ w2,
    const float* __restrict__ b2, const int* __restrict__ counts,
    const int* __restrict__ lists, const float* __restrict__ glists,
    float* __restrict__ out)
{
    const int e = blockIdx.y;
    const int count = counts[e];
    const int row0 = blockIdx.x * BM;
    if (row0 >= count) return;

    __shared__ float sX[BM * XS];
    __shared__ float sH[BM * HS];
    __shared__ int sTokF[BM];
    __shared__ float sGateF[BM];
    const int tid = threadIdx.x;

    if (tid < BM) {
        const int ri = row0 + tid;
        int tok = 0; float g = 0.f;
        if (ri < count) { tok = lists[e * TOKENS + ri]; g = glists[e * TOKENS + ri]; }
        sTokF[tid] = tok; sGateF[tid] = g;
    }
    __syncthreads();
    {
        const int r = tid >> 4, q = tid & 15;
        const float4* src = (const float4*)(x + (size_t)sTokF[r] * HID);
#pragma unroll
        for (int j = 0; j < 12; ++j) {
            const float4 v = src[q + (j << 4)];
            *(float4*)&sX[r * XS + ((q + (j << 4)) << 2)] = v;
        }
    }
    __syncthreads();

    const float* w1e = w1 + (size_t)e * HID * FFN_DIM;
    const float* w2e = w2 + (size_t)e * FFN_DIM * HID;
    const float* b1e = b1 + (size_t)e * FFN_DIM;
    const float* b2e = b2 + (size_t)e * HID;
    const int r1 = tid & 15;
    const int c0 = (tid >> 4) << 2;
    const int c2 = (tid >> 4) * 48;

    float Y[48];
#pragma unroll
    for (int j = 0; j < 48; ++j) Y[j] = 0.f;

    for (int ch = 0; ch < FFN_DIM / KC; ++ch) {
        float h0 = 0.f, h1 = 0.f, h2 = 0.f, h3 = 0.f;
        const float* w1c = w1e + ch * KC + c0;
        for (int i = 0; i < HID; i += 4) {
            const float4 xv = *(const float4*)&sX[r1 * XS + i];
            const float* wp = w1c + (size_t)i * FFN_DIM;
            const float4 wa = *(const float4*)(wp);
            const float4 wb = *(const float4*)(wp + FFN_DIM);
            const float4 wc = *(const float4*)(wp + 2 * FFN_DIM);
            const float4 wd = *(const float4*)(wp + 3 * FFN_DIM);
            h0 += xv.x * wa.x + xv.y * wb.x + xv.z * wc.x + xv.w * wd.x;
            h1 += xv.x * wa.y + xv.y * wb.y + xv.z * wc.y + xv.w * wd.y;
            h2 += xv.x * wa.z + xv.y * wb.z + xv.z * wc.z + xv.w * wd.z;
            h3 += xv.x * wa.w + xv.y * wb.w + xv.z * wc.w + xv.w * wd.w;
        }
        const int cb = ch * KC + c0;
        h0 = gelu_f(h0 + b1e[cb + 0]);
        h1 = gelu_f(h1 + b1e[cb + 1]);
        h2 = gelu_f(h2 + b1e[cb + 2]);
        h3 = gelu_f(h3 + b1e[cb + 3]);
        __syncthreads();
        *(float4*)&sH[r1 * HS + c0] = make_float4(h0, h1, h2, h3);
        __syncthreads();
        const float* w2c = w2e + (size_t)ch * KC * HID + c2;
        for (int k = 0; k < KC; ++k) {
            const float hv = sH[r1 * HS + k];
            const float4* wr = (const float4*)(w2c + (size_t)k * HID);
#pragma unroll
            for (int j4 = 0; j4 < 12; ++j4) {
                const float4 wv = wr[j4];
                Y[j4 * 4 + 0] += hv * wv.x;
                Y[j4 * 4 + 1] += hv * wv.y;
                Y[j4 * 4 + 2] += hv * wv.z;
                Y[j4 * 4 + 3] += hv * wv.w;
            }
        }
    }
    const int ri = row0 + r1;
    if (ri < count) {
        const float g = sGateF[r1];
        float* orow = out + (size_t)sTokF[r1] * HID + c2;
#pragma unroll
        for (int j = 0; j < 48; ++j)
            atomicAdd(&orow[j], g * (Y[j] + b2e[c2 + j]));
    }
}

extern "C" void kernel_launch(void* const* d_in, const int* in_sizes, int n_in,
                              void* d_out, int out_size, void* d_ws, size_t ws_size,
                              hipStream_t stream)
{
    const float* x  = (const float*)d_in[0];
    const float* rw = (const float*)d_in[1];
    const float* rb = (const float*)d_in[2];
    const float* w1 = (const float*)d_in[3];
    const float* b1 = (const float*)d_in[4];
    const float* w2 = (const float*)d_in[5];
    const float* b2 = (const float*)d_in[6];

    float* out = (float*)d_out;
    float* out_comb   = out;
    float* out_rw     = out + (size_t)TOKENS * HID;
    float* out_dm     = out_rw + (size_t)TOKENS * NEXP;
    float* out_aux    = out_dm + (size_t)TOKENS * NEXP;
    float* out_logits = out_aux + 1;

    char* ws = (char*)d_ws;
    int*   counts  = (int*)ws;
    int*   poffs   = (int*)(ws + 64);
    float* probsum = (float*)(ws + 128);
    float* gatesum = (float*)(ws + 160);
    int*   lists   = (int*)(ws + 256);
    float* glists  = (float*)(ws + 256 + (size_t)NEXP * TOKENS * 4);
    size_t off = 256 + (size_t)NEXP * TOKENS * 8;
    off = (off + 255) & ~(size_t)255;
    unsigned short* Xg  = (unsigned short*)(ws + off); off += (size_t)MAXT * 256 * HID * 2;
    unsigned short* W1T = (unsigned short*)(ws + off); off += (size_t)NEXP * HID * FFN_DIM * 2;
    unsigned short* W2T = (unsigned short*)(ws + off); off += (size_t)NEXP * HID * FFN_DIM * 2;
    unsigned short* Hbuf = (unsigned short*)(ws + off);

    // adaptive grouping: fit as many 256-row tiles of H (bf16 [rows][FFN]) as ws allows
    size_t avail = (ws_size > off) ? (ws_size - off) : 0;
    const int tilesFit = (int)(avail / ((size_t)256 * FFN_DIM * 2));
    int G = 0, tilesPG = 0;
    if (tilesFit >= 1) {
        G = (MAXT + tilesFit - 1) / tilesFit;
        tilesPG = (MAXT + G - 1) / G;
    }

    hipMemsetAsync(out_comb, 0, (size_t)TOKENS * HID * sizeof(float), stream);
    hipMemsetAsync(out_dm, 0, (size_t)TOKENS * NEXP * sizeof(float), stream);
    hipMemsetAsync(d_ws, 0, 256, stream);

    router_kernel<<<dim3(RT_BLOCKS), 512, 0, stream>>>(
        x, rw, rb, out_rw, out_dm, out_logits,
        counts, probsum, gatesum, lists, glists);
    finalize_kernel<<<1, 64, 0, stream>>>(counts, probsum, gatesum, poffs, out_aux);

    if (G > 0) {
        static int attr_done = 0;
        if (!attr_done) {
            hipFuncSetAttribute((const void*)gemm1_kernel,
                                hipFuncAttributeMaxDynamicSharedMemorySize, 147456);
            hipFuncSetAttribute((const void*)gemm2_kernel,
                                hipFuncAttributeMaxDynamicSharedMemorySize, 149504);
            attr_done = 1;
        }
        gatherx_kernel<<<dim3(MAXT * 256), 192, 0, stream>>>(
            x, counts, poffs, lists, Xg);
        convT_kernel<<<dim3(FFN_DIM / 32, HID / 64, NEXP), 256, 0, stream>>>(w1, W1T, HID, FFN_DIM);
        convT_kernel<<<dim3(HID / 32, FFN_DIM / 64, NEXP), 256, 0, stream>>>(w2, W2T, FFN_DIM, HID);
        for (int g = 0; g < G; ++g) {
            const int grBase = g * tilesPG * 256;
            gemm1_kernel<<<dim3(tilesPG * (FFN_DIM / 128)), 512, 147456, stream>>>(
                Xg, W1T, b1, poffs, Hbuf, grBase, tilesPG);
            gemm2_kernel<<<dim3(tilesPG * (HID / 128)), 512, 149504, stream>>>(
                Hbuf, W2T, b2, counts, poffs, lists, glists, out_comb, grBase, tilesPG);
        }
    } else {
        ffn_kernel<<<dim3(TOKENS / BM, NEXP), 256, 0, stream>>>(
            x, w1, b1, w2, b2, counts, lists, glists, out_comb);
    }
}

// Round 2
// 810.855 us; speedup vs baseline: 1.2451x; 1.0316x over previous
//
#include <hip/hip_runtime.h>
#include <math.h>

#define TOKENS 16384
#define HID 768
#define FFN_DIM 3072
#define NEXP 8
#define MAXT 136        // max 256-row padded tiles

#define RT_TPB 128      // router tokens per block
#define RT_BLOCKS (TOKENS / RT_TPB)

typedef __bf16 bf16x8 __attribute__((ext_vector_type(8)));
typedef float f32x4 __attribute__((ext_vector_type(4)));

#define GLOBAL_AS(p) ((const __attribute__((address_space(1))) void*)(p))
#define LDS_AS(p)    ((__attribute__((address_space(3))) void*)(p))
#define SB0 __builtin_amdgcn_sched_barrier(0)
#define VM4 asm volatile("s_waitcnt vmcnt(4)" ::: "memory")
#define VM0 asm volatile("s_waitcnt vmcnt(0)" ::: "memory")

__device__ __forceinline__ float gelu_f(float x) {
    const float x3 = x * x * x;
    const float z = 0.7978845608028654f * (x + 0.044715f * x3);
    const float e = __expf(2.f * z);
    const float t = 1.f - 2.f / (e + 1.f);   // tanh(z)
    return 0.5f * x * (1.f + t);
}

__device__ __forceinline__ unsigned short f2bf(float v) {
    return __builtin_bit_cast(unsigned short, (__bf16)v);
}

// ---------------- router (block-aggregated atomics) ----------------
__global__ void __launch_bounds__(512) router_kernel(
    const float* __restrict__ x, const float* __restrict__ rw,
    const float* __restrict__ rb,
    float* __restrict__ out_rw, float* __restrict__ out_dm,
    float* __restrict__ out_logits,
    int* __restrict__ counts, float* __restrict__ probsum,
    float* __restrict__ gatesum, int* __restrict__ lists,
    float* __restrict__ glists)
{
    __shared__ int s_cnt[NEXP], s_base[NEXP];
    __shared__ float s_prob[NEXP], s_gate[NEXP];
    __shared__ int s_e1[RT_TPB], s_s1[RT_TPB], s_e2[RT_TPB], s_s2[RT_TPB];
    __shared__ float s_g1v[RT_TPB], s_g2v[RT_TPB];

    const int tid = threadIdx.x;
    if (tid < NEXP) { s_cnt[tid] = 0; s_prob[tid] = 0.f; s_gate[tid] = 0.f; }
    __syncthreads();

    const int wave = tid >> 6, lane = tid & 63;

    for (int it = 0; it < RT_TPB / 8; ++it) {   // 16 tokens per wave
        const int lt = wave * (RT_TPB / 8) + it;
        const int t = blockIdx.x * RT_TPB + lt;
        const float* xr = x + (size_t)t * HID;
        float acc[NEXP];
#pragma unroll
        for (int e = 0; e < NEXP; ++e) acc[e] = 0.f;
#pragma unroll
        for (int j = 0; j < 12; ++j) {
            const int i = lane + (j << 6);
            const float xv = xr[i];
            const float4 a = ((const float4*)(rw + (size_t)i * NEXP))[0];
            const float4 b = ((const float4*)(rw + (size_t)i * NEXP))[1];
            acc[0] += xv * a.x; acc[1] += xv * a.y; acc[2] += xv * a.z; acc[3] += xv * a.w;
            acc[4] += xv * b.x; acc[5] += xv * b.y; acc[6] += xv * b.z; acc[7] += xv * b.w;
        }
#pragma unroll
        for (int off = 32; off > 0; off >>= 1)
#pragma unroll
            for (int e = 0; e < NEXP; ++e) acc[e] += __shfl_down(acc[e], off, 64);

        if (lane == 0) {
            float lg[NEXP];
            float m = -1e30f;
#pragma unroll
            for (int e = 0; e < NEXP; ++e) { lg[e] = acc[e] + rb[e]; m = fmaxf(m, lg[e]); }
            float ex[NEXP]; float s = 0.f;
#pragma unroll
            for (int e = 0; e < NEXP; ++e) { ex[e] = expf(lg[e] - m); s += ex[e]; }
            const float inv = 1.f / s;
            float* lrow = out_logits + (size_t)t * NEXP;
            float* prow = out_rw + (size_t)t * NEXP;
#pragma unroll
            for (int e = 0; e < NEXP; ++e) {
                lrow[e] = lg[e];
                const float p = ex[e] * inv;
                prow[e] = p;
                atomicAdd(&s_prob[e], p);
            }
            int i1 = 0;
#pragma unroll
            for (int e = 1; e < NEXP; ++e) if (lg[e] > lg[i1]) i1 = e;
            int i2 = (i1 == 0) ? 1 : 0;
#pragma unroll
            for (int e = 0; e < NEXP; ++e) if (e != i1 && lg[e] > lg[i2]) i2 = e;
            const float e2 = expf(lg[i2] - lg[i1]);
            const float g1 = 1.f / (1.f + e2);
            const float g2 = e2 / (1.f + e2);
            out_dm[(size_t)t * NEXP + i1] = g1;
            out_dm[(size_t)t * NEXP + i2] = g2;
            atomicAdd(&s_gate[i1], g1);
            atomicAdd(&s_gate[i2], g2);
            s_e1[lt] = i1; s_s1[lt] = atomicAdd(&s_cnt[i1], 1); s_g1v[lt] = g1;
            s_e2[lt] = i2; s_s2[lt] = atomicAdd(&s_cnt[i2], 1); s_g2v[lt] = g2;
        }
    }
    __syncthreads();
    if (tid < NEXP) {
        s_base[tid] = atomicAdd(&counts[tid], s_cnt[tid]);
        atomicAdd(&probsum[tid], s_prob[tid]);
        atomicAdd(&gatesum[tid], s_gate[tid]);
    }
    __syncthreads();
    if (tid < RT_TPB) {
        const int t = blockIdx.x * RT_TPB + tid;
        int e = s_e1[tid]; int p = s_base[e] + s_s1[tid];
        lists[e * TOKENS + p] = t; glists[e * TOKENS + p] = s_g1v[tid];
        e = s_e2[tid]; p = s_base[e] + s_s2[tid];
        lists[e * TOKENS + p] = t; glists[e * TOKENS + p] = s_g2v[tid];
    }
}

// ---------------- finalize: aux loss + padded (256) segment offsets ----------------
__global__ void finalize_kernel(const int* __restrict__ counts,
                                const float* __restrict__ probsum,
                                const float* __restrict__ gatesum,
                                int* __restrict__ poffs,
                                float* __restrict__ out_aux)
{
    if (threadIdx.x == 0 && blockIdx.x == 0) {
        float s = 0.f; int po = 0;
        for (int e = 0; e < NEXP; ++e) {
            poffs[e] = po;
            po += ((counts[e] + 255) >> 8) << 8;   // pad each segment to 256
            s += (probsum[e] / (float)TOKENS) * (gatesum[e] / (float)TOKENS);
        }
        poffs[NEXP] = po;
        *out_aux = s * (float)NEXP;
    }
}

// ---------------- gather X into segment order, fp32 -> bf16 ----------------
__global__ void __launch_bounds__(192) gatherx_kernel(
    const float* __restrict__ x, const int* __restrict__ counts,
    const int* __restrict__ poffs, const int* __restrict__ lists,
    unsigned short* __restrict__ Xg)
{
    const int r = blockIdx.x;
    if (r >= poffs[NEXP]) return;
    int e = 0;
#pragma unroll
    for (int q = 1; q < NEXP; ++q) e += (r >= poffs[q]);
    const int ri = r - poffs[e];
    const int tid = threadIdx.x;
    uint2 o = make_uint2(0u, 0u);
    if (ri < counts[e]) {
        const int tok = lists[e * TOKENS + ri];
        const float4 v = *(const float4*)&x[(size_t)tok * HID + tid * 4];
        o.x = (unsigned)f2bf(v.x) | ((unsigned)f2bf(v.y) << 16);
        o.y = (unsigned)f2bf(v.z) | ((unsigned)f2bf(v.w) << 16);
    }
    *(uint2*)&Xg[(size_t)r * HID + tid * 4] = o;
}

// fp32 [E][R][C] -> bf16 transposed [E][C][R]
__global__ void __launch_bounds__(256) convT_kernel(const float* __restrict__ in,
                                                    unsigned short* __restrict__ out,
                                                    int R, int C)
{
    __shared__ float sT[32][65];
    const int e = blockIdx.z;
    const float* in_e = in + (size_t)e * R * C;
    unsigned short* out_e = out + (size_t)e * R * C;
    const int r0 = blockIdx.y * 64;
    const int c0 = blockIdx.x * 32;
    const int tid = threadIdx.x;
    const int rr = tid >> 3, c4 = (tid & 7) * 4;
#pragma unroll
    for (int half = 0; half < 2; ++half) {
        const int r = rr + half * 32;
        const float4 v = *(const float4*)&in_e[(size_t)(r0 + r) * C + c0 + c4];
        sT[c4 + 0][r] = v.x; sT[c4 + 1][r] = v.y;
        sT[c4 + 2][r] = v.z; sT[c4 + 3][r] = v.w;
    }
    __syncthreads();
    const int c = tid >> 3, u = tid & 7;
    uint4 pk;
    const float* sr = &sT[c][u * 8];
    pk.x = (unsigned)f2bf(sr[0]) | ((unsigned)f2bf(sr[1]) << 16);
    pk.y = (unsigned)f2bf(sr[2]) | ((unsigned)f2bf(sr[3]) << 16);
    pk.z = (unsigned)f2bf(sr[4]) | ((unsigned)f2bf(sr[5]) << 16);
    pk.w = (unsigned)f2bf(sr[6]) | ((unsigned)f2bf(sr[7]) << 16);
    *(uint4*)&out_e[(size_t)(c0 + c) * R + r0 + u * 8] = pk;
}

// =====================================================================
// 256x256 tile, 8 waves, BK=64 split into two K-halves (half-tiles).
// 4 phases per K-tile: each phase = {ds_read chunk, stage 1 half-tile
// (2 gload_lds), [vmcnt(4) twice per K-tile], barrier, 16 MFMA under
// setprio, barrier}. Double-buffered LDS 2x64KB. Loads never drained
// to 0 mid-loop (counted vmcnt, 3-4 phases of latency cover).
// LDS buffer layout (bf16 elems): [Ak0:0][Ak1:8192][Bk0:16384][Bk1:24576].
// Swizzle: LDS linear; global source column kg=(l&3)^((l>>3)&3); read
// gpos=q4^((fr>>1)&3) -- exact involution pair, conflict-free reads.
// =====================================================================

#define STAGE_A(bufE_, kt_, kh_) do { \
    const unsigned short* _p = aStP + (size_t)(kt_) * 64 + (kh_) * 32; \
    __bf16* _d = &lds[(bufE_) + (kh_) * 8192 + wv * 1024]; \
    __builtin_amdgcn_global_load_lds(GLOBAL_AS(_p), LDS_AS(_d), 16, 0, 0); \
    __builtin_amdgcn_global_load_lds(GLOBAL_AS(_p + 16 * KS), LDS_AS(_d + 512), 16, 0, 0); \
} while (0)

#define STAGE_B(bufE_, kt_, kh_) do { \
    const unsigned short* _p = bStP + (size_t)(kt_) * 64 + (kh_) * 32; \
    __bf16* _d = &lds[(bufE_) + 16384 + (kh_) * 8192 + wv * 1024]; \
    __builtin_amdgcn_global_load_lds(GLOBAL_AS(_p), LDS_AS(_d), 16, 0, 0); \
    __builtin_amdgcn_global_load_lds(GLOBAL_AS(_p + 16 * KS), LDS_AS(_d + 512), 16, 0, 0); \
} while (0)

#define PH(MH, KH, READB, STG, VMS) do { \
    bf16x8 a_[4]; \
    _Pragma("unroll") \
    for (int _j = 0; _j < 4; ++_j) \
        a_[_j] = *(const bf16x8*)&lds[cE + (KH) * 8192 + aRd + ((MH) * 4 + _j) * 512]; \
    if (READB) { \
        _Pragma("unroll") \
        for (int _n = 0; _n < 4; ++_n) \
            b_[_n] = *(const bf16x8*)&lds[cE + (KH) * 8192 + bRd + _n * 512]; \
    } \
    STG; \
    VMS; \
    SB0; __builtin_amdgcn_s_barrier(); SB0; \
    __builtin_amdgcn_s_setprio(1); \
    _Pragma("unroll") \
    for (int _j = 0; _j < 4; ++_j) \
        _Pragma("unroll") \
        for (int _n = 0; _n < 4; ++_n) \
            acc[(MH) * 4 + _j][_n] = __builtin_amdgcn_mfma_f32_16x16x32_bf16( \
                a_[_j], b_[_n], acc[(MH) * 4 + _j][_n], 0, 0, 0); \
    __builtin_amdgcn_s_setprio(0); \
    SB0; __builtin_amdgcn_s_barrier(); SB0; \
} while (0)

// decode: bijective XCD swizzle (m204) then supertile (8 m-tiles x NT n-tiles)
#define DECODE_TILE(NT_) \
    const int nwg = gridDim.x;                                                       \
    const int orig = blockIdx.x;                                                     \
    const int qq = nwg >> 3, rr2 = nwg & 7;                                          \
    const int xcd = orig & 7, pos = orig >> 3;                                       \
    const int wid = (xcd < rr2 ? xcd * (qq + 1) : rr2 * (qq + 1) + (xcd - rr2) * qq) + pos; \
    const int nSuper = tilesPG >> 3;                                                 \
    const int fullB = nSuper * 8 * (NT_);                                            \
    int mt, nti;                                                                     \
    if (wid < fullB) {                                                               \
        const int st_ = wid / (8 * (NT_));                                           \
        const int lo = wid - st_ * (8 * (NT_));                                      \
        mt = (st_ << 3) + (lo & 7);                                                  \
        nti = lo >> 3;                                                               \
    } else {                                                                         \
        const int rem = tilesPG - (nSuper << 3);                                     \
        const int lo = wid - fullB;                                                  \
        mt = (nSuper << 3) + lo % rem;                                               \
        nti = lo / rem;                                                              \
    }

// ---------------- GEMM1: H = gelu(Xg @ W1 + b1), bf16 out ----------------
__global__ void __launch_bounds__(512, 2) gemm1_kernel(
    const unsigned short* __restrict__ Xg, const unsigned short* __restrict__ W1T,
    const float* __restrict__ b1, const int* __restrict__ poffs,
    unsigned short* __restrict__ H, int grBase, int tilesPG)
{
    extern __shared__ __bf16 lds[];
    const int KS = HID;            // 768
    const int NKT = HID / 64;      // 12

    DECODE_TILE(FFN_DIM / 256)     // 12 n-tiles
    const int gr = grBase + mt * 256;
    if (gr >= poffs[NEXP]) return;
    int e = 0;
#pragma unroll
    for (int q = 1; q < NEXP; ++q) e += (gr >= poffs[q]);
    const int hbase = gr - grBase;
    const int n0 = nti * 256;

    const int tid = threadIdx.x;
    const int wv = tid >> 6, lane = tid & 63;
    const int wr = wv >> 2, wc = wv & 3;
    const int fr = lane & 15, q4 = lane >> 4;
    const int rowoff = lane >> 2;
    const int swzW = ((lane & 3) ^ ((lane >> 3) & 3)) << 3;     // global src col (elems)
    const int swzR = ((q4 ^ ((fr >> 1) & 3)) << 3);             // lds read col (elems)

    const unsigned short* aStP = Xg + (size_t)(gr + wv * 32 + rowoff) * KS + swzW;
    const unsigned short* bStP = W1T + (size_t)e * (HID * FFN_DIM)
                               + (size_t)(n0 + wv * 32 + rowoff) * KS + swzW;

    const int aRd = (wr * 128 + fr) * 32 + swzR;
    const int bRd = 16384 + (wc * 64 + fr) * 32 + swzR;

    f32x4 acc[8][4];
#pragma unroll
    for (int i = 0; i < 8; ++i)
#pragma unroll
        for (int j = 0; j < 4; ++j) acc[i][j] = (f32x4)(0.f);
    bf16x8 b_[4];

    // prologue: stage K-tile 0 into buf0
    STAGE_A(0, 0, 0); STAGE_B(0, 0, 0); STAGE_A(0, 0, 1); STAGE_B(0, 0, 1);
    VM4;
    SB0; __builtin_amdgcn_s_barrier(); SB0;

#pragma unroll 2
    for (int kt = 0; kt < NKT; ++kt) {
        const int cE = (kt & 1) << 15;
        const int nE = cE ^ 32768;
        const int kn = kt + 1;
        const bool st = (kn < NKT);
        PH(0, 0, 1, if (st) STAGE_A(nE, kn, 0), ((void)0));
        PH(1, 0, 0, if (st) STAGE_B(nE, kn, 0), if (st) { VM4; } else { VM0; });
        PH(0, 1, 1, if (st) STAGE_A(nE, kn, 1), ((void)0));
        PH(1, 1, 0, if (st) STAGE_B(nE, kn, 1), if (st) { VM4; });
    }

    const float* b1e = b1 + (size_t)e * FFN_DIM;
    float bias[4];
#pragma unroll
    for (int nj = 0; nj < 4; ++nj) bias[nj] = b1e[n0 + wc * 64 + nj * 16 + fr];
#pragma unroll
    for (int mi = 0; mi < 8; ++mi) {
#pragma unroll
        for (int r = 0; r < 4; ++r) {
            const int m = wr * 128 + mi * 16 + q4 * 4 + r;
            unsigned short* hp = H + (size_t)(hbase + m) * FFN_DIM + n0 + wc * 64 + fr;
#pragma unroll
            for (int nj = 0; nj < 4; ++nj)
                hp[nj * 16] = f2bf(gelu_f(acc[mi][nj][r] + bias[nj]));
        }
    }
}

// ---------------- GEMM2: out[tok] += gate*(H @ W2 + b2) ----------------
__global__ void __launch_bounds__(512, 2) gemm2_kernel(
    const unsigned short* __restrict__ H, const unsigned short* __restrict__ W2T,
    const float* __restrict__ b2, const int* __restrict__ counts,
    const int* __restrict__ poffs, const int* __restrict__ lists,
    const float* __restrict__ glists, float* __restrict__ out,
    int grBase, int tilesPG)
{
    extern __shared__ __bf16 lds[];
    const int KS = FFN_DIM;          // 3072
    const int NKT = FFN_DIM / 64;    // 48

    DECODE_TILE(HID / 256)           // 3 n-tiles
    const int gr = grBase + mt * 256;
    if (gr >= poffs[NEXP]) return;
    int e = 0;
#pragma unroll
    for (int q = 1; q < NEXP; ++q) e += (gr >= poffs[q]);
    const int cnt = counts[e];
    const int m0 = gr - poffs[e];
    const int hbase = gr - grBase;
    const int n0 = nti * 256;

    const int tid = threadIdx.x;
    const int wv = tid >> 6, lane = tid & 63;
    const int wr = wv >> 2, wc = wv & 3;
    const int fr = lane & 15, q4 = lane >> 4;
    const int rowoff = lane >> 2;
    const int swzW = ((lane & 3) ^ ((lane >> 3) & 3)) << 3;
    const int swzR = ((q4 ^ ((fr >> 1) & 3)) << 3);

    const unsigned short* aStP = H + (size_t)(hbase + wv * 32 + rowoff) * KS + swzW;
    const unsigned short* bStP = W2T + (size_t)e * (HID * FFN_DIM)
                               + (size_t)(n0 + wv * 32 + rowoff) * KS + swzW;

    const int aRd = (wr * 128 + fr) * 32 + swzR;
    const int bRd = 16384 + (wc * 64 + fr) * 32 + swzR;

    f32x4 acc[8][4];
#pragma unroll
    for (int i = 0; i < 8; ++i)
#pragma unroll
        for (int j = 0; j < 4; ++j) acc[i][j] = (f32x4)(0.f);
    bf16x8 b_[4];

    STAGE_A(0, 0, 0); STAGE_B(0, 0, 0); STAGE_A(0, 0, 1); STAGE_B(0, 0, 1);
    VM4;
    SB0; __builtin_amdgcn_s_barrier(); SB0;

#pragma unroll 2
    for (int kt = 0; kt < NKT; ++kt) {
        const int cE = (kt & 1) << 15;
        const int nE = cE ^ 32768;
        const int kn = kt + 1;
        const bool st = (kn < NKT);
        PH(0, 0, 1, if (st) STAGE_A(nE, kn, 0), ((void)0));
        PH(1, 0, 0, if (st) STAGE_B(nE, kn, 0), if (st) { VM4; } else { VM0; });
        PH(0, 1, 1, if (st) STAGE_A(nE, kn, 1), ((void)0));
        PH(1, 1, 0, if (st) STAGE_B(nE, kn, 1), if (st) { VM4; });
    }

    int* sTok = (int*)&lds[65536];          // byte 131072
    float* sGate = (float*)&lds[66048];     // byte 132096
    if (tid < 256) {
        int ri = m0 + tid; if (ri > cnt - 1) ri = cnt - 1;
        sTok[tid] = lists[e * TOKENS + ri];
        sGate[tid] = glists[e * TOKENS + ri];
    }
    __syncthreads();

    const float* b2e = b2 + (size_t)e * HID;
    float bias[4];
#pragma unroll
    for (int nj = 0; nj < 4; ++nj) bias[nj] = b2e[n0 + wc * 64 + nj * 16 + fr];
#pragma unroll
    for (int mi = 0; mi < 8; ++mi) {
#pragma unroll
        for (int r = 0; r < 4; ++r) {
            const int m = wr * 128 + mi * 16 + q4 * 4 + r;
            if (m0 + m < cnt) {
                const int tok = sTok[m];
                const float g = sGate[m];
                float* orow = out + (size_t)tok * HID + n0 + wc * 64 + fr;
#pragma unroll
                for (int nj = 0; nj < 4; ++nj)
                    atomicAdd(&orow[nj * 16], g * (acc[mi][nj][r] + bias[nj]));
            }
        }
    }
}

// ---------------- fallback fp32 FFN (ws too small) ----------------
#define BM 16
#define KC 64
#define XS 772
#define HS 68
__global__ void __launch_bounds__(256) ffn_kernel(
    const float* __restrict__ x, const float* __restrict__ w1,
    const float* __restrict__ b1, const float* __restrict__ w2,
    const float* __restrict__ b2, const int* __restrict__ counts,
    const int* __restrict__ lists, const float* __restrict__ glists,
    float* __restrict__ out)
{
    const int e = blockIdx.y;
    const int count = counts[e];
    const int row0 = blockIdx.x * BM;
    if (row0 >= count) return;

    __shared__ float sX[BM * XS];
    __shared__ float sH[BM * HS];
    __shared__ int sTokF[BM];
    __shared__ float sGateF[BM];
    const int tid = threadIdx.x;

    if (tid < BM) {
        const int ri = row0 + tid;
        int tok = 0; float g = 0.f;
        if (ri < count) { tok = lists[e * TOKENS + ri]; g = glists[e * TOKENS + ri]; }
        sTokF[tid] = tok; sGateF[tid] = g;
    }
    __syncthreads();
    {
        const int r = tid >> 4, q = tid & 15;
        const float4* src = (const float4*)(x + (size_t)sTokF[r] * HID);
#pragma unroll
        for (int j = 0; j < 12; ++j) {
            const float4 v = src[q + (j << 4)];
            *(float4*)&sX[r * XS + ((q + (j << 4)) << 2)] = v;
        }
    }
    __syncthreads();

    const float* w1e = w1 + (size_t)e * HID * FFN_DIM;
    const float* w2e = w2 + (size_t)e * FFN_DIM * HID;
    const float* b1e = b1 + (size_t)e * FFN_DIM;
    const float* b2e = b2 + (size_t)e * HID;
    const int r1 = tid & 15;
    const int c0 = (tid >> 4) << 2;
    const int c2 = (tid >> 4) * 48;

    float Y[48];
#pragma unroll
    for (int j = 0; j < 48; ++j) Y[j] = 0.f;

    for (int ch = 0; ch < FFN_DIM / KC; ++ch) {
        float h0 = 0.f, h1 = 0.f, h2 = 0.f, h3 = 0.f;
        const float* w1c = w1e + ch * KC + c0;
        for (int i = 0; i < HID; i += 4) {
            const float4 xv = *(const float4*)&sX[r1 * XS + i];
            const float* wp = w1c + (size_t)i * FFN_DIM;
            const float4 wa = *(const float4*)(wp);
            const float4 wb = *(const float4*)(wp + FFN_DIM);
            const float4 wc = *(const float4*)(wp + 2 * FFN_DIM);
            const float4 wd = *(const float4*)(wp + 3 * FFN_DIM);
            h0 += xv.x * wa.x + xv.y * wb.x + xv.z * wc.x + xv.w * wd.x;
            h1 += xv.x * wa.y + xv.y * wb.y + xv.z * wc.y + xv.w * wd.y;
            h2 += xv.x * wa.z + xv.y * wb.z + xv.z * wc.z + xv.w * wd.z;
            h3 += xv.x * wa.w + xv.y * wb.w + xv.z * wc.w + xv.w * wd.w;
        }
        const int cb = ch * KC + c0;
        h0 = gelu_f(h0 + b1e[cb + 0]);
        h1 = gelu_f(h1 + b1e[cb + 1]);
        h2 = gelu_f(h2 + b1e[cb + 2]);
        h3 = gelu_f(h3 + b1e[cb + 3]);
        __syncthreads();
        *(float4*)&sH[r1 * HS + c0] = make_float4(h0, h1, h2, h3);
        __syncthreads();
        const float* w2c = w2e + (size_t)ch * KC * HID + c2;
        for (int k = 0; k < KC; ++k) {
            const float hv = sH[r1 * HS + k];
            const float4* wr = (const float4*)(w2c + (size_t)k * HID);
#pragma unroll
            for (int j4 = 0; j4 < 12; ++j4) {
                const float4 wv = wr[j4];
                Y[j4 * 4 + 0] += hv * wv.x;
                Y[j4 * 4 + 1] += hv * wv.y;
                Y[j4 * 4 + 2] += hv * wv.z;
                Y[j4 * 4 + 3] += hv * wv.w;
            }
        }
    }
    const int ri = row0 + r1;
    if (ri < count) {
        const float g = sGateF[r1];
        float* orow = out + (size_t)sTokF[r1] * HID + c2;
#pragma unroll
        for (int j = 0; j < 48; ++j)
            atomicAdd(&orow[j], g * (Y[j] + b2e[c2 + j]));
    }
}

extern "C" void kernel_launch(void* const* d_in, const int* in_sizes, int n_in,
                              void* d_out, int out_size, void* d_ws, size_t ws_size,
                              hipStream_t stream)
{
    const float* x  = (const float*)d_in[0];
    const float* rw = (const float*)d_in[1];
    const float* rb = (const float*)d_in[2];
    const float* w1 = (const float*)d_in[3];
    const float* b1 = (const float*)d_in[4];
    const float* w2 = (const float*)d_in[5];
    const float* b2 = (const float*)d_in[6];

    float* out = (float*)d_out;
    float* out_comb   = out;
    float* out_rw     = out + (size_t)TOKENS * HID;
    float* out_dm     = out_rw + (size_t)TOKENS * NEXP;
    float* out_aux    = out_dm + (size_t)TOKENS * NEXP;
    float* out_logits = out_aux + 1;

    char* ws = (char*)d_ws;
    int*   counts  = (int*)ws;
    int*   poffs   = (int*)(ws + 64);
    float* probsum = (float*)(ws + 128);
    float* gatesum = (float*)(ws + 160);
    int*   lists   = (int*)(ws + 256);
    float* glists  = (float*)(ws + 256 + (size_t)NEXP * TOKENS * 4);
    size_t off = 256 + (size_t)NEXP * TOKENS * 8;
    off = (off + 255) & ~(size_t)255;
    unsigned short* Xg  = (unsigned short*)(ws + off); off += (size_t)MAXT * 256 * HID * 2;
    unsigned short* W1T = (unsigned short*)(ws + off); off += (size_t)NEXP * HID * FFN_DIM * 2;
    unsigned short* W2T = (unsigned short*)(ws + off); off += (size_t)NEXP * HID * FFN_DIM * 2;
    unsigned short* Hbuf = (unsigned short*)(ws + off);

    // adaptive grouping: fit as many 256-row tiles of H (bf16 [rows][FFN]) as ws allows
    size_t avail = (ws_size > off) ? (ws_size - off) : 0;
    const int tilesFit = (int)(avail / ((size_t)256 * FFN_DIM * 2));
    int G = 0, tilesPG = 0;
    if (tilesFit >= 1) {
        G = (MAXT + tilesFit - 1) / tilesFit;
        tilesPG = (MAXT + G - 1) / G;
    }

    hipMemsetAsync(out_comb, 0, (size_t)TOKENS * HID * sizeof(float), stream);
    hipMemsetAsync(out_dm, 0, (size_t)TOKENS * NEXP * sizeof(float), stream);
    hipMemsetAsync(d_ws, 0, 256, stream);

    router_kernel<<<dim3(RT_BLOCKS), 512, 0, stream>>>(
        x, rw, rb, out_rw, out_dm, out_logits,
        counts, probsum, gatesum, lists, glists);
    finalize_kernel<<<1, 64, 0, stream>>>(counts, probsum, gatesum, poffs, out_aux);

    if (G > 0) {
        static int attr_done = 0;
        if (!attr_done) {
            hipFuncSetAttribute((const void*)gemm1_kernel,
                                hipFuncAttributeMaxDynamicSharedMemorySize, 131072);
            hipFuncSetAttribute((const void*)gemm2_kernel,
                                hipFuncAttributeMaxDynamicSharedMemorySize, 133120);
            attr_done = 1;
        }
        gatherx_kernel<<<dim3(MAXT * 256), 192, 0, stream>>>(
            x, counts, poffs, lists, Xg);
        convT_kernel<<<dim3(FFN_DIM / 32, HID / 64, NEXP), 256, 0, stream>>>(w1, W1T, HID, FFN_DIM);
        convT_kernel<<<dim3(HID / 32, FFN_DIM / 64, NEXP), 256, 0, stream>>>(w2, W2T, FFN_DIM, HID);
        for (int g = 0; g < G; ++g) {
            const int grBase = g * tilesPG * 256;
            gemm1_kernel<<<dim3(tilesPG * (FFN_DIM / 256)), 512, 131072, stream>>>(
                Xg, W1T, b1, poffs, Hbuf, grBase, tilesPG);
            gemm2_kernel<<<dim3(tilesPG * (HID / 256)), 512, 133120, stream>>>(
                Hbuf, W2T, b2, counts, poffs, lists, glists, out_comb, grBase, tilesPG);
        }
    } else {
        ffn_kernel<<<dim3(TOKENS / BM, NEXP), 256, 0, stream>>>(
            x, w1, b1, w2, b2, counts, lists, glists, out_comb);
    }
}